// Round 17
// baseline (139.358 us; speedup 1.0000x reference)
//
#include <hip/hip_runtime.h>
#include <math.h>

#define V 8192
#define D 128
#define NH 8
#define HD 16
#define SEQ 128
#define HID 341
#define EPS 1e-6f

__device__ __forceinline__ float sigm(float x) { return 1.0f / (1.0f + __expf(-x)); }

// 1024-thread block-wide sum. scratch >= 16 floats. 2 barriers.
__device__ __forceinline__ float block_sum1024(float v, float* scratch) {
    #pragma unroll
    for (int m = 32; m > 0; m >>= 1) v += __shfl_xor(v, m);
    if ((threadIdx.x & 63) == 0) scratch[threadIdx.x >> 6] = v;
    __syncthreads();
    float s = ((scratch[0] + scratch[1]) + (scratch[2] + scratch[3])) +
              ((scratch[4] + scratch[5]) + (scratch[6] + scratch[7])) +
              ((scratch[8] + scratch[9]) + (scratch[10] + scratch[11])) +
              ((scratch[12] + scratch[13]) + (scratch[14] + scratch[15]));
    __syncthreads();
    return s;
}

// K1 (lean): embed + rms + qkv + rope. grid = SEQ + 128, block = 1024.
// Blocks 0..127: one row each (load-at-use QKV, 3 full-depth dot groups).
// Blocks 128..255: warm-stream all weights (6 MB) in ONE scheduling round.
__global__ __launch_bounds__(1024, 4) void k_embed_qkv(
    const int* __restrict__ idx, const float* __restrict__ w_raw,
    const float* __restrict__ wq, const float* __restrict__ wk,
    const float* __restrict__ wv, const float* __restrict__ n1w,
    const float* __restrict__ w1, const float* __restrict__ w3,
    const float* __restrict__ w2, const float* __restrict__ wo,
    float* __restrict__ x, float* __restrict__ q, float* __restrict__ k,
    float* __restrict__ v, float* __restrict__ sink) {
    int t = threadIdx.x;
    if (blockIdx.x >= SEQ) {
        // L3-warm: 128 blocks x 1024 threads stream every weight once
        int g = (blockIdx.x - SEQ) * 1024 + t;  // 0..131071
        float acc = 0.f;
        const float4* p = (const float4*)w_raw;  // 262144 float4
        for (int i = g; i < 262144; i += 131072) {
            float4 u = p[i];
            acc += u.x + u.y + u.z + u.w;
        }
        p = (const float4*)w1;  // 21824 float4 (both layers)
        if (g < 21824) { float4 u = p[g]; acc += u.x + u.y + u.z + u.w; }
        p = (const float4*)w3;
        if (g < 21824) { float4 u = p[g]; acc += u.x + u.y + u.z + u.w; }
        p = (const float4*)w2;
        if (g < 21824) { float4 u = p[g]; acc += u.x + u.y + u.z + u.w; }
        p = (const float4*)wq;  // 8192 float4 (both layers)
        if (g < 8192) { float4 u = p[g]; acc += u.x + u.y + u.z + u.w; }
        p = (const float4*)wk;
        if (g < 8192) { float4 u = p[g]; acc += u.x + u.y + u.z + u.w; }
        p = (const float4*)wv;
        if (g < 8192) { float4 u = p[g]; acc += u.x + u.y + u.z + u.w; }
        p = (const float4*)wo;
        if (g < 8192) { float4 u = p[g]; acc += u.x + u.y + u.z + u.w; }
        if (acc == 1234.5678f) sink[0] = acc;  // never true; defeats DCE
        return;
    }
    __shared__ float hr[D], qrow[D], krow[D], vrow[D], scr[16];
    int s = blockIdx.x;
    int col = t & 127, g8 = t >> 7;
    // embed gather (critical path) issued first
    float xv = 0.f;
    if (t < 128) {
        xv = sigm(w_raw[t * V + idx[s]]);
        x[s * D + t] = xv;
    }
    float ss = block_sum1024((t < 128) ? xv * xv : 0.f, scr);
    float r = 1.0f / sqrtf(ss * (1.0f / D) + EPS);
    if (t < 128) hr[t] = xv * r * n1w[t];
    __syncthreads();
    // QKV: groups 0=q, 1=k, 2=v (full 128-deep dots), 3..7 idle
    float qk = 0.f;
    if (g8 < 3) {
        const float* wsel = (g8 == 0) ? wq : ((g8 == 1) ? wk : wv);
        float a0 = 0, a1 = 0, a2 = 0, a3 = 0;
        #pragma unroll 8
        for (int d = 0; d < D; d += 4) {
            a0 += hr[d] * wsel[d * D + col];
            a1 += hr[d + 1] * wsel[(d + 1) * D + col];
            a2 += hr[d + 2] * wsel[(d + 2) * D + col];
            a3 += hr[d + 3] * wsel[(d + 3) * D + col];
        }
        qk = (a0 + a1) + (a2 + a3);
    }
    if (g8 == 0) qrow[col] = qk;
    else if (g8 == 1) krow[col] = qk;
    else if (g8 == 2) vrow[col] = qk;
    __syncthreads();
    if (t < 128) {
        v[s * D + t] = vrow[t];
        int c = t & (HD - 1);
        int m = c >> 1;
        float fr = (float)s * expf(-(float)m * 1.15129254649702283e+00f);
        float cs = cosf(fr), sn = sinf(fr);
        int base = t & ~1;
        float qe = qrow[base], qod = qrow[base + 1];
        float ke = krow[base], kod = krow[base + 1];
        q[s * D + t] = (c & 1) ? (qe * sn + qod * cs) : (qe * cs - qod * sn);
        k[s * D + t] = (c & 1) ? (ke * sn + kod * cs) : (ke * cs - kod * sn);
    }
}

// K2/K3: fused layer per row. grid=SEQ, block=1024 (16 waves, 4 waves/SIMD).
// No register-prefetch arrays (R11 lesson: compiler sinks/spills them);
// weights loaded at use with unrolled batching, latency hidden by 4-wave TLP.
template <int MODE>
__global__ __launch_bounds__(1024, 4) void k_layer(
    const float* __restrict__ q, const float* __restrict__ kg,
    const float* __restrict__ vg, float* __restrict__ x,
    const float* __restrict__ wo, const float* __restrict__ n2w,
    const float* __restrict__ w1, const float* __restrict__ w3,
    const float* __restrict__ w2, const float* __restrict__ wq,
    const float* __restrict__ wk, const float* __restrict__ wv,
    const float* __restrict__ n1w, float* __restrict__ qo, float* __restrict__ ko,
    float* __restrict__ vo, const float* __restrict__ fw, float* __restrict__ xng) {
    __shared__ float ps[NH][SEQ + 1];
    __shared__ float qs[D], orow[D], h2[D];
    __shared__ float part[8][D];
    __shared__ float afA[HID], afB[HID], af[HID];
    __shared__ float rl[NH];
    __shared__ float scr[16];
    int s = blockIdx.x, t = threadIdx.x;
    int col = t & 127, g8 = t >> 7;  // g8 in 0..7
    int jlo = g8 * 16, dlo = g8 * 16;

    float qv = 0.f, xr = 0.f;
    if (t < 128) {
        qv = q[s * D + t];
        xr = x[s * D + t];
        qs[t] = qv;
    }
    __syncthreads();

    // scores: thread (j=col, h=g8), 16-deep dot; zero-fill j>s
    {
        const float4* kp = (const float4*)&kg[col * D + g8 * HD];
        float4 k0 = kp[0], k1v = kp[1], k2v = kp[2], k3v = kp[3];
        const float* qh = &qs[g8 * HD];
        float acc = k0.x * qh[0] + k0.y * qh[1] + k0.z * qh[2] + k0.w * qh[3] +
                    k1v.x * qh[4] + k1v.y * qh[5] + k1v.z * qh[6] + k1v.w * qh[7] +
                    k2v.x * qh[8] + k2v.y * qh[9] + k2v.z * qh[10] + k2v.w * qh[11] +
                    k3v.x * qh[12] + k3v.y * qh[13] + k3v.z * qh[14] + k3v.w * qh[15];
        ps[g8][col] = (col <= s) ? acc * 0.25f : 0.f;
    }
    __syncthreads();

    // softmax over j<=s: waves 0..7, head h = t>>6, full wave per head
    if (t < 512) {
        int h = t >> 6, lane = t & 63;
        float pm = -1e30f;
        for (int j = lane; j <= s; j += 64) pm = fmaxf(pm, ps[h][j]);
        #pragma unroll
        for (int m = 32; m > 0; m >>= 1) pm = fmaxf(pm, __shfl_xor(pm, m));
        float psum = 0.f;
        for (int j = lane; j <= s; j += 64) {
            float e = __expf(ps[h][j] - pm);
            ps[h][j] = e;
            psum += e;
        }
        #pragma unroll
        for (int m = 32; m > 0; m >>= 1) psum += __shfl_xor(psum, m);
        if (lane == 0) rl[h] = 1.0f / psum;
    }
    __syncthreads();

    // o partials: h = col>>4, j in [jlo, jlo+16); V loaded at use (coalesced)
    {
        int h = col >> 4;
        float a0 = 0, a1 = 0, a2 = 0, a3 = 0;
        #pragma unroll
        for (int j = 0; j < 16; j += 4) {
            a0 += ps[h][jlo + j] * vg[(jlo + j) * D + col];
            a1 += ps[h][jlo + j + 1] * vg[(jlo + j + 1) * D + col];
            a2 += ps[h][jlo + j + 2] * vg[(jlo + j + 2) * D + col];
            a3 += ps[h][jlo + j + 3] * vg[(jlo + j + 3) * D + col];
        }
        part[g8][col] = (a0 + a1) + (a2 + a3);
    }
    __syncthreads();
    if (t < 128)
        orow[t] = (((part[0][t] + part[1][t]) + (part[2][t] + part[3][t])) +
                   ((part[4][t] + part[5][t]) + (part[6][t] + part[7][t]))) * rl[t >> 4];
    __syncthreads();

    // wo: u in [dlo, dlo+16), loaded at use (coalesced)
    {
        float a0 = 0, a1 = 0;
        #pragma unroll
        for (int u = 0; u < 16; u += 2) {
            a0 += orow[dlo + u] * wo[(dlo + u) * D + col];
            a1 += orow[dlo + u + 1] * wo[(dlo + u + 1) * D + col];
        }
        part[g8][col] = a0 + a1;
    }
    __syncthreads();
    float xn = 0.f;
    if (t < 128)
        xn = xr + ((part[0][t] + part[1][t]) + (part[2][t] + part[3][t])) +
             ((part[4][t] + part[5][t]) + (part[6][t] + part[7][t]));
    float ss2 = block_sum1024((t < 128) ? xn * xn : 0.f, scr);
    float r2 = 1.0f / sqrtf(ss2 * (1.0f / D) + EPS);
    if (t < 128) h2[t] = xn * r2 * n2w[t];
    __syncthreads();

    // FFN1: 682 column-tasks, SINGLE round (t < 682)
    if (t < 2 * HID) {
        int mat = t >= HID;
        int c2 = mat ? (t - HID) : t;
        const float* w = mat ? w3 : w1;
        float a0 = 0, a1 = 0, a2 = 0, a3 = 0;
        #pragma unroll 8
        for (int d = 0; d < D; d += 4) {
            a0 += h2[d] * w[d * HID + c2];
            a1 += h2[d + 1] * w[(d + 1) * HID + c2];
            a2 += h2[d + 2] * w[(d + 2) * HID + c2];
            a3 += h2[d + 3] * w[(d + 3) * HID + c2];
        }
        if (mat) afB[c2] = (a0 + a1) + (a2 + a3);
        else afA[c2] = (a0 + a1) + (a2 + a3);
    }
    __syncthreads();
    if (t < HID) {
        float a1v = afA[t];
        af[t] = (a1v / (1.0f + __expf(-a1v))) * afB[t];
    }
    __syncthreads();

    // FFN2: col output, 341-sum split 8-way (43 each, last 40)
    {
        int lo = g8 * 43;
        int hi = (lo + 43 > HID) ? HID : lo + 43;
        float a0 = 0, a1 = 0, a2 = 0, a3 = 0;
        int tt = lo;
        #pragma unroll 8
        for (; tt + 3 < hi; tt += 4) {
            a0 += af[tt] * w2[tt * D + col];
            a1 += af[tt + 1] * w2[(tt + 1) * D + col];
            a2 += af[tt + 2] * w2[(tt + 2) * D + col];
            a3 += af[tt + 3] * w2[(tt + 3) * D + col];
        }
        for (; tt < hi; ++tt) a0 += af[tt] * w2[tt * D + col];
        part[g8][col] = (a0 + a1) + (a2 + a3);
    }
    __syncthreads();
    float x2 = 0.f;
    if (t < 128) {
        x2 = xn + ((part[0][t] + part[1][t]) + (part[2][t] + part[3][t])) +
             ((part[4][t] + part[5][t]) + (part[6][t] + part[7][t]));
        if (MODE == 0) x[s * D + t] = x2;
    }

    float ss = block_sum1024((t < 128) ? x2 * x2 : 0.f, scr);
    float r = 1.0f / sqrtf(ss * (1.0f / D) + EPS);

    if constexpr (MODE == 0) {
        if (t < 128) h2[t] = x2 * r * n1w[t];
        __syncthreads();
        // next-layer QKV: groups 0=q, 1=k, 2=v (full 128-deep dots), 3..7 idle
        float qk = 0.f;
        if (g8 < 3) {
            const float* wsel = (g8 == 0) ? wq : ((g8 == 1) ? wk : wv);
            float a0 = 0, a1 = 0, a2 = 0, a3 = 0;
            #pragma unroll 8
            for (int d = 0; d < D; d += 4) {
                a0 += h2[d] * wsel[d * D + col];
                a1 += h2[d + 1] * wsel[(d + 1) * D + col];
                a2 += h2[d + 2] * wsel[(d + 2) * D + col];
                a3 += h2[d + 3] * wsel[(d + 3) * D + col];
            }
            qk = (a0 + a1) + (a2 + a3);
        }
        if (g8 == 0) qs[col] = qk;
        else if (g8 == 1) orow[col] = qk;
        else if (g8 == 2) part[0][col] = qk;
        __syncthreads();
        if (t < 128) {
            vo[s * D + t] = part[0][t];
            int c = t & (HD - 1);
            int mm = c >> 1;
            float fr = (float)s * expf(-(float)mm * 1.15129254649702283e+00f);
            float cs = cosf(fr), sn = sinf(fr);
            int base = t & ~1;
            float qe = qs[base], qod = qs[base + 1];
            float ke = orow[base], kod = orow[base + 1];
            qo[s * D + t] = (c & 1) ? (qe * sn + qod * cs) : (qe * cs - qod * sn);
            ko[s * D + t] = (c & 1) ? (ke * sn + kod * cs) : (ke * cs - kod * sn);
        }
    } else {
        float y = (t < 128) ? x2 * r * fw[t] : 0.f;
        float nn = block_sum1024(y * y, scr);
        if (t < 128) xng[t * SEQ + s] = y / sqrtf(nn);
    }
}

// K4: logits[s,v] = clip(mean_d(xn[s,d] <= vn[v,d] ? 1 : vn[v,d]))
__global__ __launch_bounds__(256) void k_logits(const float* __restrict__ xng,
                                                const float* __restrict__ w_raw,
                                                float* __restrict__ out) {
    __shared__ float xs[D * 64];
    __shared__ float vs[D * 32];
    __shared__ float nred[256];
    __shared__ float invn_s[32];
    int t = threadIdx.x;
    int sbase = (blockIdx.x & 1) * 64;
    int vbase = (blockIdx.x >> 1) * 32;
    for (int i = t; i < D * 64; i += 256) {
        int d = i >> 6, s2 = i & 63;
        xs[i] = xng[d * SEQ + sbase + s2];
    }
    for (int i = t; i < D * 32; i += 256) {
        int d = i >> 5, jj = i & 31;
        vs[i] = sigm(w_raw[d * V + vbase + jj]);
    }
    __syncthreads();
    {
        int colc = t & 31, dp = t >> 5;
        float p = 0.f;
        for (int u = 0; u < 16; ++u) {
            float vv = vs[(dp * 16 + u) * 32 + colc];
            p += vv * vv;
        }
        nred[t] = p;
    }
    __syncthreads();
    if (t < 32) {
        float sum = 0.f;
        for (int u = 0; u < 8; ++u) sum += nred[u * 32 + t];
        invn_s[t] = 1.0f / sqrtf(sum);
    }
    __syncthreads();
    for (int i = t; i < D * 32; i += 256) vs[i] *= invn_s[i & 31];
    __syncthreads();
    int vg = t & 15;
    int sg = t >> 4;
    float acc[4][2] = {};
    for (int d = 0; d < D; ++d) {
        float4 xq = *(const float4*)&xs[d * 64 + sg * 4];
        float2 vq = *(const float2*)&vs[d * 32 + vg * 2];
        acc[0][0] += (xq.x <= vq.x) ? 1.0f : vq.x;
        acc[0][1] += (xq.x <= vq.y) ? 1.0f : vq.y;
        acc[1][0] += (xq.y <= vq.x) ? 1.0f : vq.x;
        acc[1][1] += (xq.y <= vq.y) ? 1.0f : vq.y;
        acc[2][0] += (xq.z <= vq.x) ? 1.0f : vq.x;
        acc[2][1] += (xq.z <= vq.y) ? 1.0f : vq.y;
        acc[3][0] += (xq.w <= vq.x) ? 1.0f : vq.x;
        acc[3][1] += (xq.w <= vq.y) ? 1.0f : vq.y;
    }
    const float inv128 = 1.0f / 128.0f;
    #pragma unroll
    for (int si = 0; si < 4; ++si) {
        int s = sbase + sg * 4 + si;
        float2 ov;
        ov.x = fminf(fmaxf(acc[si][0] * inv128, 1e-6f), 1.0f - 1e-6f);
        ov.y = fminf(fmaxf(acc[si][1] * inv128, 1e-6f), 1.0f - 1e-6f);
        *(float2*)&out[s * V + vbase + vg * 2] = ov;
    }
}

extern "C" void kernel_launch(void* const* d_in, const int* in_sizes, int n_in,
                              void* d_out, int out_size, void* d_ws, size_t ws_size,
                              hipStream_t stream) {
    const int* idx = (const int*)d_in[0];
    const float* w_raw = (const float*)d_in[1];
    const float* n1w = (const float*)d_in[2];
    const float* n2w = (const float*)d_in[3];
    const float* wq = (const float*)d_in[4];
    const float* wk = (const float*)d_in[5];
    const float* wv = (const float*)d_in[6];
    const float* wo = (const float*)d_in[7];
    const float* w1 = (const float*)d_in[8];
    const float* w3 = (const float*)d_in[9];
    const float* w2 = (const float*)d_in[10];
    const float* fnw = (const float*)d_in[11];
    float* out = (float*)d_out;
    float* ws = (float*)d_ws;

    float* x    = ws;
    float* q1   = ws + 16384;
    float* k1   = ws + 32768;
    float* v1   = ws + 49152;
    float* q2   = ws + 65536;
    float* k2   = ws + 81920;
    float* v2   = ws + 98304;
    float* xng  = ws + 114688;
    float* sink = ws + 131072;

    k_embed_qkv<<<dim3(SEQ + 128), dim3(1024), 0, stream>>>(
        idx, w_raw, wq, wk, wv, n1w, w1, w3, w2, wo, x, q1, k1, v1, sink);
    k_layer<0><<<dim3(SEQ), dim3(1024), 0, stream>>>(
        q1, k1, v1, x, wo, n2w, w1, w3, w2,
        wq + D * D, wk + D * D, wv + D * D, n1w + D, q2, k2, v2,
        (const float*)nullptr, (float*)nullptr);
    k_layer<1><<<dim3(SEQ), dim3(1024), 0, stream>>>(
        q2, k2, v2, x, wo + D * D, n2w + D, w1 + D * HID, w3 + D * HID,
        w2 + HID * D, (const float*)nullptr, (const float*)nullptr,
        (const float*)nullptr, (const float*)nullptr, (float*)nullptr,
        (float*)nullptr, (float*)nullptr, fnw, xng);
    k_logits<<<dim3(512), dim3(256), 0, stream>>>(xng, w_raw, out);
}